// Round 4
// baseline (112.496 us; speedup 1.0000x reference)
//
#include <hip/hip_runtime.h>
#include <hip/hip_bf16.h>

// B=16, N=1024, M=8192.
//   d[b,n,m] = || binder[b,n,:] - target[m,:] ||
//   attract[b] = mean of 204 smallest (min_m d) over n;  repel[b] = sum relu(3-d)^2
//   out[b] = 10*attract + 5*repel
//
// R4 changes (R3 post-mortem: pair loop ~39 VALU/iter; reduce had LDS-atomic
// contention + 64 barriers):
//  - dot-product form: stage (-2t, |t|^2), precompute |x|^2 -> 4 VALU/pair
//    (was 6). Clamp d2>=0 before sqrt/atomicMin (cancellation ~5e-5).
//  - reduce: single-wave 31-step bit-bisection per batch (16 vals/lane in
//    registers, shuffle reduce). No barriers, no LDS, no atomics. Exact.

#define BB 16
#define NN 1024
#define MM 8192
#define MT 64           // targets per chunk
#define MC (MM / MT)    // 128 m-chunks
#define KSEL 204        // int(0.2 * 1024)

__global__ __launch_bounds__(256, 8) void binder_pair_kernel(
    const float* __restrict__ binder,   // [B, N, 3]
    const float* __restrict__ target,   // [M, 3]
    unsigned* __restrict__ min_u,       // [B, N] uint bits of min d^2 (pre-init 0xFF..)
    float* __restrict__ repel_part)     // [B, MC]
{
    __shared__ float4 s4[MT];           // (-2tx, -2ty, -2tz, |t|^2)
    __shared__ float wred[4];

    const int mc  = blockIdx.x;
    const int b   = blockIdx.y;
    const int tid = threadIdx.x;

    if (tid < MT) {
        const float* tp = target + (mc * MT + tid) * 3;
        const float tx = tp[0], ty = tp[1], tz = tp[2];
        s4[tid] = make_float4(-2.0f * tx, -2.0f * ty, -2.0f * tz,
                              fmaf(tx, tx, fmaf(ty, ty, tz * tz)));
    }
    __syncthreads();

    // 4 binder points per thread; 48B contiguous/lane, 16B-aligned.
    const float* bp = binder + ((size_t)b * NN + tid * 4) * 3;
    const float4 f0 = ((const float4*)bp)[0];
    const float4 f1 = ((const float4*)bp)[1];
    const float4 f2 = ((const float4*)bp)[2];
    const float x0 = f0.x, y0 = f0.y, z0 = f0.z;
    const float x1 = f0.w, y1 = f1.x, z1 = f1.y;
    const float x2 = f1.z, y2 = f1.w, z2 = f2.x;
    const float x3 = f2.y, y3 = f2.z, z3 = f2.w;
    const float q0 = fmaf(x0, x0, fmaf(y0, y0, z0 * z0));
    const float q1 = fmaf(x1, x1, fmaf(y1, y1, z1 * z1));
    const float q2 = fmaf(x2, x2, fmaf(y2, y2, z2 * z2));
    const float q3 = fmaf(x3, x3, fmaf(y3, y3, z3 * z3));

    float m0 = 3.4e38f, m1 = 3.4e38f, m2 = 3.4e38f, m3 = 3.4e38f;
    float repel = 0.0f;

#pragma unroll 4
    for (int m = 0; m < MT; ++m) {
        const float4 s = s4[m];   // wave-uniform addr -> broadcast b128
        const float d0 = fmaf(s.x, x0, fmaf(s.y, y0, fmaf(s.z, z0, s.w + q0)));
        const float d1 = fmaf(s.x, x1, fmaf(s.y, y1, fmaf(s.z, z1, s.w + q1)));
        const float d2 = fmaf(s.x, x2, fmaf(s.y, y2, fmaf(s.z, z2, s.w + q2)));
        const float d3 = fmaf(s.x, x3, fmaf(s.y, y3, fmaf(s.z, z3, s.w + q3)));
        m0 = fminf(m0, d0);
        m1 = fminf(m1, d1);
        m2 = fminf(m2, d2);
        m3 = fminf(m3, d3);
        const float mm = fminf(fminf(d0, d1), fminf(d2, d3));
        if (__any(mm < 9.0f)) {   // rare clash path (~47% of wave-iters)
            const float c0 = fmaxf(3.0f - __builtin_amdgcn_sqrtf(fmaxf(d0, 0.0f)), 0.0f);
            const float c1 = fmaxf(3.0f - __builtin_amdgcn_sqrtf(fmaxf(d1, 0.0f)), 0.0f);
            const float c2 = fmaxf(3.0f - __builtin_amdgcn_sqrtf(fmaxf(d2, 0.0f)), 0.0f);
            const float c3 = fmaxf(3.0f - __builtin_amdgcn_sqrtf(fmaxf(d3, 0.0f)), 0.0f);
            repel = fmaf(c0, c0, repel);
            repel = fmaf(c1, c1, repel);
            repel = fmaf(c2, c2, repel);
            repel = fmaf(c3, c3, repel);
        }
    }

    // clamp tiny negatives from cancellation, then deterministic uint atomicMin
    unsigned* mp = min_u + (size_t)b * NN + tid * 4;
    atomicMin(&mp[0], __float_as_uint(fmaxf(m0, 0.0f)));
    atomicMin(&mp[1], __float_as_uint(fmaxf(m1, 0.0f)));
    atomicMin(&mp[2], __float_as_uint(fmaxf(m2, 0.0f)));
    atomicMin(&mp[3], __float_as_uint(fmaxf(m3, 0.0f)));

    // repel block-reduce: wave shuffle then 4-slot LDS
#pragma unroll
    for (int off = 32; off > 0; off >>= 1) repel += __shfl_down(repel, off);
    if ((tid & 63) == 0) wred[tid >> 6] = repel;
    __syncthreads();
    if (tid == 0) repel_part[b * MC + mc] = wred[0] + wred[1] + wred[2] + wred[3];
}

// One wave per batch. 16 values/lane in registers; 31-step bisection on the
// (monotonic, non-negative) float bit patterns finds the exact KSEL-th
// smallest; sum = sum_{u<T} sqrt(u) + (KSEL - cnt_less)*sqrt(T). No LDS.
__global__ __launch_bounds__(64) void binder_reduce_kernel(
    const unsigned* __restrict__ min_u,    // [B, N] bits of min d^2
    const float* __restrict__ repel_part,  // [B, MC]
    float* __restrict__ out)               // [B]
{
    const int b    = blockIdx.x;
    const int lane = threadIdx.x;

    unsigned u[16];
    const uint4* base = (const uint4*)(min_u + (size_t)b * NN) + lane * 4;
    const uint4 a0 = base[0], a1 = base[1], a2 = base[2], a3 = base[3];
    u[0] = a0.x; u[1] = a0.y; u[2]  = a0.z; u[3]  = a0.w;
    u[4] = a1.x; u[5] = a1.y; u[6]  = a1.z; u[7]  = a1.w;
    u[8] = a2.x; u[9] = a2.y; u[10] = a2.z; u[11] = a2.w;
    u[12] = a3.x; u[13] = a3.y; u[14] = a3.z; u[15] = a3.w;

    // invariant: count(u < lo) < KSEL. After loop lo == KSEL-th smallest.
    unsigned lo = 0u;
    for (int bit = 30; bit >= 0; --bit) {
        const unsigned mid = lo | (1u << bit);
        int c = 0;
#pragma unroll
        for (int i = 0; i < 16; ++i) c += (u[i] < mid) ? 1 : 0;
#pragma unroll
        for (int off = 32; off > 0; off >>= 1) c += __shfl_down(c, off);
        c = __shfl(c, 0);
        if (c < KSEL) lo = mid;
    }

    float sum = 0.0f;
    int   cl  = 0;
#pragma unroll
    for (int i = 0; i < 16; ++i) {
        if (u[i] < lo) {
            sum += __builtin_amdgcn_sqrtf(__uint_as_float(u[i]));
            ++cl;
        }
    }
#pragma unroll
    for (int off = 32; off > 0; off >>= 1) {
        sum += __shfl_down(sum, off);
        cl  += __shfl_down(cl, off);
    }

    float r = repel_part[b * MC + lane] + repel_part[b * MC + 64 + lane];
#pragma unroll
    for (int off = 32; off > 0; off >>= 1) r += __shfl_down(r, off);

    if (lane == 0) {
        const float total = sum + (float)(KSEL - cl)
                                  * __builtin_amdgcn_sqrtf(__uint_as_float(lo));
        out[b] = 10.0f * (total / (float)KSEL) + 5.0f * r;
    }
}

extern "C" void kernel_launch(void* const* d_in, const int* in_sizes, int n_in,
                              void* d_out, int out_size, void* d_ws, size_t ws_size,
                              hipStream_t stream) {
    const float* binder = (const float*)d_in[0];   // [16,1024,3] fp32
    const float* target = (const float*)d_in[1];   // [8192,3]   fp32
    float* out = (float*)d_out;                    // [16]       fp32

    unsigned* min_u   = (unsigned*)d_ws;                               // 64 KB
    float* repel_part = (float*)((char*)d_ws + (size_t)BB * NN * sizeof(unsigned));

    // 0xFFFFFFFF == uint "+inf" for the atomicMin fold (capture-safe)
    hipMemsetAsync(min_u, 0xFF, (size_t)BB * NN * sizeof(unsigned), stream);

    dim3 g1(MC, BB);   // 128 x 16 = 2048 blocks
    binder_pair_kernel<<<g1, 256, 0, stream>>>(binder, target, min_u, repel_part);
    binder_reduce_kernel<<<BB, 64, 0, stream>>>(min_u, repel_part, out);
}

// Round 5
// 109.431 us; speedup vs baseline: 1.0280x; 1.0280x over previous
//
#include <hip/hip_runtime.h>
#include <hip/hip_bf16.h>

// B=16, N=1024, M=8192.
//   d[b,n,m] = || binder[b,n,:] - target[m,:] ||
//   attract[b] = mean of 204 smallest (min_m d) over n;  repel[b] = sum relu(3-d)^2
//   out[b] = 10*attract + 5*repel
//
// R5 change (R4 post-mortem: VALU cut was neutral, VALUBusy fell 73->64% --
// pair kernel is NOT VALU-bound; WRITE_SIZE 33.6MB for 8.4MB of atomicMin
// payload = cross-XCD line ping-pong on the 64KB min_u region):
//  - NO atomics. Pair kernel stores per-chunk mins as one coalesced float4
//    per thread into min_part[B][MC][N] (plain dwordx4, zero contention).
//  - Reduce kernel folds the MC=128 rows with coalesced float4 loads,
//    stages 1024 folded values in LDS, then each wave runs the 31-step
//    bit-bisection redundantly on 16 vals/lane (barrier-free, identical
//    result), sums k-smallest exactly. No memset dispatch needed anymore.

#define BB 16
#define NN 1024
#define MM 8192
#define MT 64           // targets per chunk
#define MC (MM / MT)    // 128 m-chunks
#define KSEL 204        // int(0.2 * 1024)

__global__ __launch_bounds__(256, 8) void binder_pair_kernel(
    const float* __restrict__ binder,   // [B, N, 3]
    const float* __restrict__ target,   // [M, 3]
    float* __restrict__ min_part,       // [B, MC, N] min d^2 per chunk
    float* __restrict__ repel_part)     // [B, MC]
{
    __shared__ float4 s4[MT];           // (-2tx, -2ty, -2tz, |t|^2)
    __shared__ float wred[4];

    const int mc  = blockIdx.x;
    const int b   = blockIdx.y;
    const int tid = threadIdx.x;

    if (tid < MT) {
        const float* tp = target + (mc * MT + tid) * 3;
        const float tx = tp[0], ty = tp[1], tz = tp[2];
        s4[tid] = make_float4(-2.0f * tx, -2.0f * ty, -2.0f * tz,
                              fmaf(tx, tx, fmaf(ty, ty, tz * tz)));
    }
    __syncthreads();

    // 4 binder points per thread; 48B contiguous/lane, 16B-aligned.
    const float* bp = binder + ((size_t)b * NN + tid * 4) * 3;
    const float4 f0 = ((const float4*)bp)[0];
    const float4 f1 = ((const float4*)bp)[1];
    const float4 f2 = ((const float4*)bp)[2];
    const float x0 = f0.x, y0 = f0.y, z0 = f0.z;
    const float x1 = f0.w, y1 = f1.x, z1 = f1.y;
    const float x2 = f1.z, y2 = f1.w, z2 = f2.x;
    const float x3 = f2.y, y3 = f2.z, z3 = f2.w;
    const float q0 = fmaf(x0, x0, fmaf(y0, y0, z0 * z0));
    const float q1 = fmaf(x1, x1, fmaf(y1, y1, z1 * z1));
    const float q2 = fmaf(x2, x2, fmaf(y2, y2, z2 * z2));
    const float q3 = fmaf(x3, x3, fmaf(y3, y3, z3 * z3));

    float m0 = 3.4e38f, m1 = 3.4e38f, m2 = 3.4e38f, m3 = 3.4e38f;
    float repel = 0.0f;

#pragma unroll 4
    for (int m = 0; m < MT; ++m) {
        const float4 s = s4[m];   // wave-uniform addr -> broadcast b128
        const float d0 = fmaf(s.x, x0, fmaf(s.y, y0, fmaf(s.z, z0, s.w + q0)));
        const float d1 = fmaf(s.x, x1, fmaf(s.y, y1, fmaf(s.z, z1, s.w + q1)));
        const float d2 = fmaf(s.x, x2, fmaf(s.y, y2, fmaf(s.z, z2, s.w + q2)));
        const float d3 = fmaf(s.x, x3, fmaf(s.y, y3, fmaf(s.z, z3, s.w + q3)));
        m0 = fminf(m0, d0);
        m1 = fminf(m1, d1);
        m2 = fminf(m2, d2);
        m3 = fminf(m3, d3);
        const float mm = fminf(fminf(d0, d1), fminf(d2, d3));
        if (__any(mm < 9.0f)) {   // clash path (~47% of wave-iters)
            const float c0 = fmaxf(3.0f - __builtin_amdgcn_sqrtf(fmaxf(d0, 0.0f)), 0.0f);
            const float c1 = fmaxf(3.0f - __builtin_amdgcn_sqrtf(fmaxf(d1, 0.0f)), 0.0f);
            const float c2 = fmaxf(3.0f - __builtin_amdgcn_sqrtf(fmaxf(d2, 0.0f)), 0.0f);
            const float c3 = fmaxf(3.0f - __builtin_amdgcn_sqrtf(fmaxf(d3, 0.0f)), 0.0f);
            repel = fmaf(c0, c0, repel);
            repel = fmaf(c1, c1, repel);
            repel = fmaf(c2, c2, repel);
            repel = fmaf(c3, c3, repel);
        }
    }

    // coalesced plain store: lane-contiguous float4, no contention, exact.
    // clamp tiny negatives from the dot-form cancellation.
    const float4 mout = make_float4(fmaxf(m0, 0.0f), fmaxf(m1, 0.0f),
                                    fmaxf(m2, 0.0f), fmaxf(m3, 0.0f));
    ((float4*)min_part)[(size_t)(b * MC + mc) * (NN / 4) + tid] = mout;

    // repel block-reduce: wave shuffle then 4-slot LDS
#pragma unroll
    for (int off = 32; off > 0; off >>= 1) repel += __shfl_down(repel, off);
    if ((tid & 63) == 0) wred[tid >> 6] = repel;
    __syncthreads();
    if (tid == 0) repel_part[b * MC + mc] = wred[0] + wred[1] + wred[2] + wred[3];
}

// One block (256 thr) per batch. Fold MC rows -> 4 vals/thread, stage in LDS,
// per-wave redundant 31-step bit-bisection (no barriers in the loop), exact
// sum of KSEL smallest + ties. Then repel partial fold. Deterministic.
__global__ __launch_bounds__(256) void binder_reduce_kernel(
    const float* __restrict__ min_part,    // [B, MC, N]
    const float* __restrict__ repel_part,  // [B, MC]
    float* __restrict__ out)               // [B]
{
    __shared__ unsigned us[NN];
    __shared__ float wsum[4];
    __shared__ int   wcnt[4];
    __shared__ float rsum;

    const int b    = blockIdx.x;
    const int tid  = threadIdx.x;
    const int lane = tid & 63;
    const int wid  = tid >> 6;

    // fold chunk mins: 128 coalesced float4 loads per thread (independent,
    // pipelined; 512KB/block, L2-resident)
    const float4* mp = (const float4*)min_part + (size_t)b * MC * (NN / 4) + tid;
    float4 a = mp[0];
    for (int c = 1; c < MC; ++c) {
        const float4 q = mp[(size_t)c * (NN / 4)];
        a.x = fminf(a.x, q.x); a.y = fminf(a.y, q.y);
        a.z = fminf(a.z, q.z); a.w = fminf(a.w, q.w);
    }
    unsigned u[4] = {__float_as_uint(a.x), __float_as_uint(a.y),
                     __float_as_uint(a.z), __float_as_uint(a.w)};
    us[tid * 4 + 0] = u[0];
    us[tid * 4 + 1] = u[1];
    us[tid * 4 + 2] = u[2];
    us[tid * 4 + 3] = u[3];
    __syncthreads();

    // each wave loads all 1024 values, 16/lane, stride-64 (conflict-free)
    unsigned ub[16];
#pragma unroll
    for (int i = 0; i < 16; ++i) ub[i] = us[lane + 64 * i];

    // bisection: invariant count(x < lo) < KSEL; final lo = KSEL-th smallest.
    unsigned lo = 0u;
    for (int bit = 30; bit >= 0; --bit) {
        const unsigned mid = lo | (1u << bit);
        int c = 0;
#pragma unroll
        for (int i = 0; i < 16; ++i) c += (ub[i] < mid) ? 1 : 0;
#pragma unroll
        for (int off = 32; off > 0; off >>= 1) c += __shfl_down(c, off);
        c = __shfl(c, 0);
        if (c < KSEL) lo = mid;
    }
    // all waves computed identical lo (same data, same algorithm)

    // sum of values strictly below lo over this thread's 4 distinct values
    float sum = 0.0f;
    int   cl  = 0;
#pragma unroll
    for (int i = 0; i < 4; ++i) {
        if (u[i] < lo) {
            sum += __builtin_amdgcn_sqrtf(__uint_as_float(u[i]));
            ++cl;
        }
    }
#pragma unroll
    for (int off = 32; off > 0; off >>= 1) {
        sum += __shfl_down(sum, off);
        cl  += __shfl_down(cl, off);
    }
    if (lane == 0) { wsum[wid] = sum; wcnt[wid] = cl; }

    // repel partials: wave 0 reduces 128 values
    if (wid == 0) {
        float r = repel_part[b * MC + lane] + repel_part[b * MC + 64 + lane];
#pragma unroll
        for (int off = 32; off > 0; off >>= 1) r += __shfl_down(r, off);
        if (lane == 0) rsum = r;
    }
    __syncthreads();

    if (tid == 0) {
        const float total = wsum[0] + wsum[1] + wsum[2] + wsum[3];
        const int   cnt   = wcnt[0] + wcnt[1] + wcnt[2] + wcnt[3];
        const float att   = total + (float)(KSEL - cnt)
                                    * __builtin_amdgcn_sqrtf(__uint_as_float(lo));
        out[b] = 10.0f * (att / (float)KSEL) + 5.0f * rsum;
    }
}

extern "C" void kernel_launch(void* const* d_in, const int* in_sizes, int n_in,
                              void* d_out, int out_size, void* d_ws, size_t ws_size,
                              hipStream_t stream) {
    const float* binder = (const float*)d_in[0];   // [16,1024,3] fp32
    const float* target = (const float*)d_in[1];   // [8192,3]   fp32
    float* out = (float*)d_out;                    // [16]       fp32

    float* min_part   = (float*)d_ws;   // B*MC*N floats = 8 MiB
    float* repel_part = (float*)((char*)d_ws + (size_t)BB * MC * NN * sizeof(float));

    dim3 g1(MC, BB);   // 128 x 16 = 2048 blocks
    binder_pair_kernel<<<g1, 256, 0, stream>>>(binder, target, min_part, repel_part);
    binder_reduce_kernel<<<BB, 256, 0, stream>>>(min_part, repel_part, out);
}